// Round 13
// baseline (263.987 us; speedup 1.0000x reference)
//
#include <hip/hip_runtime.h>
#include <hip/hip_bf16.h>

typedef unsigned short u16;
typedef short s16x8 __attribute__((ext_vector_type(8)));
typedef float f32x4 __attribute__((ext_vector_type(4)));

#define MFMA_BF16(a, b, c) __builtin_amdgcn_mfma_f32_16x16x32_bf16((a), (b), (c), 0, 0, 0)

static constexpr int D_IN   = 64;
static constexpr int H_DIM  = 512;
static constexpr int M_TILE = 64;   // samples per block
static constexpr int AST    = 520;  // LDS row stride (bf16), rows = samples
static constexpr int XST    = 72;   // x-tile row stride

__device__ __forceinline__ u16 f2bf(float f) {
  unsigned u = __builtin_bit_cast(unsigned, f);
  u += 0x7fffu + ((u >> 16) & 1u);   // RNE
  return (u16)(u >> 16);
}
__device__ __forceinline__ float bfb2f(unsigned bits16) {
  return __builtin_bit_cast(float, bits16 << 16);
}
__device__ __forceinline__ float fast_tanh(float x) {
  float e = __expf(2.0f * x);
  return 1.0f - 2.0f * __builtin_amdgcn_rcpf(e + 1.0f);
}
// packed f32x2 -> bf16x2 (RNE). gfx950 has v_cvt_pk_bf16_f32; guarded fallback.
#if defined(__gfx950__) && __has_builtin(__builtin_amdgcn_cvt_pk_bf16_f32)
__device__ __forceinline__ unsigned pk2bf(float a, float b) {
  typedef __bf16 bf16x2_t __attribute__((ext_vector_type(2)));
  bf16x2_t v = __builtin_amdgcn_cvt_pk_bf16_f32(a, b);
  return __builtin_bit_cast(unsigned, v);
}
#else
__device__ __forceinline__ unsigned pk2bf(float a, float b) {
  return (unsigned)f2bf(a) | ((unsigned)f2bf(b) << 16);
}
#endif

// ---- prep: fp32 weights -> bf16, frag-packed (idx=lane&15, k=quad*8+j) ----
// Same packing as rounds 1-12 (proven); now consumed as the A-operand of the
// TRANSPOSED GEMMs (compute h^T: M=feature, N=sample).
// W3 is folded into p2b (bwd GEMM3's A = W2[n][m]*W3[m]) -> gone from kernel.
// ws layout (bf16): p0f[64x512] p0b[512x64] p1f p1b p2f p2b  (~2.2MB)
__global__ void prep_weights(const float* __restrict__ W0,
                             const float* __restrict__ W1,
                             const float* __restrict__ W2,
                             const float* __restrict__ W3,
                             u16* __restrict__ ws) {
  u16* p0f = ws;                       // fwd W0^T: M=512 feat, K=64
  u16* p0b = p0f + D_IN * H_DIM;       // GEMM5: M=64 gradH-col, K=512
  u16* p1f = p0b + D_IN * H_DIM;
  u16* p1b = p1f + H_DIM * H_DIM;
  u16* p2f = p1b + H_DIM * H_DIM;
  u16* p2b = p2f + H_DIM * H_DIM;

  int t = blockIdx.x * 256 + threadIdx.x;   // 32768 threads
  int lane = t & 63;
  int kc   = (t >> 6) & 15;
  int ntg  = t >> 10;                       // 0..31
  int ln = lane & 15, q = lane >> 4;
  int n = ntg * 16 + ln;                    // feature index (frag idx)
  int k = kc * 32 + q * 8;

  #pragma unroll
  for (int j = 0; j < 8; ++j) {
    p1f[t * 8 + j] = f2bf(W1[(k + j) * 512 + n]);            // A[m=n][k] = W1^T
    p2f[t * 8 + j] = f2bf(W2[(k + j) * 512 + n]);
    p1b[t * 8 + j] = f2bf(W1[n * 512 + (k + j)]);            // A[n][m] = W1
    p2b[t * 8 + j] = f2bf(W2[n * 512 + (k + j)] * W3[k + j]); // W3 folded
  }
  if (kc < 2) {  // W0^T fwd: K=64
    int t0 = (ntg * 2 + kc) * 64 + lane;
    #pragma unroll
    for (int j = 0; j < 8; ++j)
      p0f[t0 * 8 + j] = f2bf(W0[(k + j) * 512 + n]);
  }
  if (ntg < 4) { // GEMM5: A[d][m] = W0[d][m], d<64
    int t0 = (ntg * 16 + kc) * 64 + lane;
    #pragma unroll
    for (int j = 0; j < 8; ++j)
      p0b[t0 * 8 + j] = f2bf(W0[n * 512 + (k + j)]);
  }
}

// Wave's 4 A-tiles (weights) of k-chunk KC -> VGPRs, contiguous 1KB each.
#define LOAD_W4(BP, KC, WA)                                                     \
  {                                                                             \
    const u16* _sr = (BP) + ((size_t)wave << 15) + ((KC) << 9) + lane * 8;      \
    _Pragma("unroll")                                                           \
    for (int s = 0; s < 4; ++s)                                                 \
      (WA)[s] = *(const s16x8*)(_sr + (s << 13));                               \
  }
#define WA_PROLOGUE3(BP)                                                        \
  { LOAD_W4(BP, 0, wa0); LOAD_W4(BP, 1, wa1); LOAD_W4(BP, 2, wa2); }

// One K-step: B-frags (activations, 4 sample-tiles) from LDS, 16 MFMAs,
// refill WA with chunk KC+3.  D[feat][sample] = W-frag x h-frag.
#define STEP3(KC, WA, BP)                                                       \
  {                                                                             \
    s16x8 b[4];                                                                 \
    _Pragma("unroll")                                                           \
    for (int nt = 0; nt < 4; ++nt)                                              \
      b[nt] = *(const s16x8*)(buf + (nt * 16 + ln) * AST + (KC) * 32 + q * 8);  \
    _Pragma("unroll")                                                           \
    for (int nt = 0; nt < 4; ++nt)                                              \
      _Pragma("unroll")                                                         \
      for (int mt = 0; mt < 4; ++mt)                                            \
        acc[mt][nt] = MFMA_BF16((WA)[mt], b[nt], acc[mt][nt]);                  \
    if ((KC) + 3 < 16) LOAD_W4(BP, (KC) + 3, WA);                               \
  }

#define GEMM512_REG(BP)                                                         \
  {                                                                             \
    STEP3( 0, wa0, BP); STEP3( 1, wa1, BP); STEP3( 2, wa2, BP);                 \
    STEP3( 3, wa0, BP); STEP3( 4, wa1, BP); STEP3( 5, wa2, BP);                 \
    STEP3( 6, wa0, BP); STEP3( 7, wa1, BP); STEP3( 8, wa2, BP);                 \
    STEP3( 9, wa0, BP); STEP3(10, wa1, BP); STEP3(11, wa2, BP);                 \
    STEP3(12, wa0, BP); STEP3(13, wa1, BP); STEP3(14, wa2, BP);                 \
    STEP3(15, wa0, BP);                                                         \
  }

// acc init = bias broadcast (C-rows are features -> bias varies with q*4+r):
// one float4 load per m-tile, replaces zero-init + epilogue adds.
#define ACC_INIT_BIAS(BIAS)                                                     \
  {                                                                             \
    _Pragma("unroll")                                                           \
    for (int mt = 0; mt < 4; ++mt) {                                            \
      float4 bv = *(const float4*)((BIAS) + wave * 64 + mt * 16 + q * 4);       \
      _Pragma("unroll")                                                         \
      for (int nt = 0; nt < 4; ++nt)                                            \
        acc[mt][nt] = (f32x4){bv.x, bv.y, bv.z, bv.w};                          \
    }                                                                           \
  }
#define ACC_INIT_ZERO()                                                         \
  {                                                                             \
    _Pragma("unroll") for (int mt = 0; mt < 4; ++mt)                            \
      _Pragma("unroll") for (int nt = 0; nt < 4; ++nt)                          \
        acc[mt][nt] = (f32x4){0.f, 0.f, 0.f, 0.f};                              \
  }

// block=512 (8 waves); wave = 64 features x 64 samples (4 m x 4 n tiles).
// Transposed orientation: lane's 4 C-values = 4 consecutive FEATURES ->
// epilogue LDS writes are ds_write_b64 (16/epilogue vs 64 scalar b16 before).
__global__ __launch_bounds__(512, 2) void hnn_fused(
    const float* __restrict__ x,
    const float* __restrict__ bias0,
    const float* __restrict__ bias1,
    const float* __restrict__ bias2,
    const u16* __restrict__ ws,
    float* __restrict__ out)
{
  const u16* p0f = ws;
  const u16* p0b = p0f + D_IN * H_DIM;
  const u16* p1f = p0b + D_IN * H_DIM;
  const u16* p1b = p1f + H_DIM * H_DIM;
  const u16* p2f = p1b + H_DIM * H_DIM;
  const u16* p2b = p2f + H_DIM * H_DIM;

  __shared__ __align__(16) u16 xs[M_TILE * XST];    // 9 KB  [sample][in-feat]
  __shared__ __align__(16) u16 buf[M_TILE * AST];   // 65 KB [sample][feat]

  const int tid  = threadIdx.x;
  const int wave = tid >> 6;      // 0..7 -> owns features wave*64..+63
  const int lane = tid & 63;
  const int ln   = lane & 15;
  const int q    = lane >> 4;
  const int m0   = wave * 64;     // wave's feature base
  const int row0 = blockIdx.x * M_TILE;

  // ---- stage x tile: 64x64 fp32 -> bf16 LDS [sample][feat] ----
  {
    int r = tid >> 3, c = (tid & 7) * 8;
    const float4* src = (const float4*)(x + (size_t)(row0 + r) * D_IN + c);
    float4 f0 = src[0];
    float4 f1 = src[1];
    u16* dst = xs + r * XST + c;
    dst[0] = f2bf(f0.x); dst[1] = f2bf(f0.y); dst[2] = f2bf(f0.z); dst[3] = f2bf(f0.w);
    dst[4] = f2bf(f1.x); dst[5] = f2bf(f1.y); dst[6] = f2bf(f1.z); dst[7] = f2bf(f1.w);
  }
  __syncthreads();

  f32x4 acc[4][4];
  s16x8 wa0[4], wa1[4], wa2[4];   // 3-deep weight (A-operand) rotation
  unsigned h0p[4][4][2];          // h packed bf16x2, C-layout (tanh' in bwd)
  unsigned h1p[4][4][2];

  // ================ GEMM0': z0^T = W0^T x^T + b0 (K=64) ================
  ACC_INIT_BIAS(bias0);
  {
    const u16* ap0 = p0f + (wave << 12) + lane * 8;
    #pragma unroll
    for (int kc = 0; kc < 2; ++kc) {
      s16x8 b[4];
      #pragma unroll
      for (int nt = 0; nt < 4; ++nt)
        b[nt] = *(const s16x8*)(xs + (nt * 16 + ln) * XST + kc * 32 + q * 8);
      #pragma unroll
      for (int mt = 0; mt < 4; ++mt) {
        s16x8 a = *(const s16x8*)(ap0 + (mt << 10) + (kc << 9));
        #pragma unroll
        for (int nt = 0; nt < 4; ++nt)
          acc[mt][nt] = MFMA_BF16(a, b[nt], acc[mt][nt]);
      }
    }
  }
  WA_PROLOGUE3(p1f);   // prefetch GEMM1 weights; overlaps epilogue VALU
  // epilogue: h0 = tanh(z0) -> pack regs + one b64 LDS write per tile
  #pragma unroll
  for (int mt = 0; mt < 4; ++mt)
    #pragma unroll
    for (int nt = 0; nt < 4; ++nt) {
      unsigned p01 = pk2bf(fast_tanh(acc[mt][nt][0]), fast_tanh(acc[mt][nt][1]));
      unsigned p23 = pk2bf(fast_tanh(acc[mt][nt][2]), fast_tanh(acc[mt][nt][3]));
      h0p[mt][nt][0] = p01; h0p[mt][nt][1] = p23;
      *(uint2*)(buf + (nt * 16 + ln) * AST + m0 + mt * 16 + q * 4) =
          make_uint2(p01, p23);
    }
  __syncthreads();

  // ================ GEMM1': z1^T = W1^T h0^T + b1 ================
  ACC_INIT_BIAS(bias1);
  GEMM512_REG(p1f);
  __syncthreads();       // all waves done reading h0 (buf)
  WA_PROLOGUE3(p2f);
  #pragma unroll
  for (int mt = 0; mt < 4; ++mt)
    #pragma unroll
    for (int nt = 0; nt < 4; ++nt) {
      unsigned p01 = pk2bf(fast_tanh(acc[mt][nt][0]), fast_tanh(acc[mt][nt][1]));
      unsigned p23 = pk2bf(fast_tanh(acc[mt][nt][2]), fast_tanh(acc[mt][nt][3]));
      h1p[mt][nt][0] = p01; h1p[mt][nt][1] = p23;
      *(uint2*)(buf + (nt * 16 + ln) * AST + m0 + mt * 16 + q * 4) =
          make_uint2(p01, p23);
    }
  __syncthreads();

  // ================ GEMM2': z2^T ; gz2° = (1-h2^2)  (W3 folded in p2b) ======
  ACC_INIT_BIAS(bias2);
  GEMM512_REG(p2f);
  __syncthreads();
  WA_PROLOGUE3(p2b);
  #pragma unroll
  for (int mt = 0; mt < 4; ++mt)
    #pragma unroll
    for (int nt = 0; nt < 4; ++nt) {
      float t0 = fast_tanh(acc[mt][nt][0]), t1 = fast_tanh(acc[mt][nt][1]);
      float t2 = fast_tanh(acc[mt][nt][2]), t3 = fast_tanh(acc[mt][nt][3]);
      unsigned p01 = pk2bf(1.0f - t0 * t0, 1.0f - t1 * t1);
      unsigned p23 = pk2bf(1.0f - t2 * t2, 1.0f - t3 * t3);
      *(uint2*)(buf + (nt * 16 + ln) * AST + m0 + mt * 16 + q * 4) =
          make_uint2(p01, p23);
    }
  __syncthreads();

  // ================ GEMM3': g1^T = (W2*W3) gz2°^T ; gz1 = g1*(1-h1^2) =======
  ACC_INIT_ZERO();
  GEMM512_REG(p2b);
  __syncthreads();
  WA_PROLOGUE3(p1b);
  #pragma unroll
  for (int mt = 0; mt < 4; ++mt)
    #pragma unroll
    for (int nt = 0; nt < 4; ++nt) {
      unsigned pa = h1p[mt][nt][0], pb = h1p[mt][nt][1];
      float h0v = bfb2f(pa & 0xffffu), h1v = bfb2f(pa >> 16);
      float h2v = bfb2f(pb & 0xffffu), h3v = bfb2f(pb >> 16);
      unsigned p01 = pk2bf(acc[mt][nt][0] * (1.0f - h0v * h0v),
                           acc[mt][nt][1] * (1.0f - h1v * h1v));
      unsigned p23 = pk2bf(acc[mt][nt][2] * (1.0f - h2v * h2v),
                           acc[mt][nt][3] * (1.0f - h3v * h3v));
      *(uint2*)(buf + (nt * 16 + ln) * AST + m0 + mt * 16 + q * 4) =
          make_uint2(p01, p23);
    }
  __syncthreads();

  // ================ GEMM4': g0^T = W1 gz1^T ; gz0 = g0*(1-h0^2) =============
  ACC_INIT_ZERO();
  GEMM512_REG(p1b);
  __syncthreads();
  #pragma unroll
  for (int mt = 0; mt < 4; ++mt)
    #pragma unroll
    for (int nt = 0; nt < 4; ++nt) {
      unsigned pa = h0p[mt][nt][0], pb = h0p[mt][nt][1];
      float h0v = bfb2f(pa & 0xffffu), h1v = bfb2f(pa >> 16);
      float h2v = bfb2f(pb & 0xffffu), h3v = bfb2f(pb >> 16);
      unsigned p01 = pk2bf(acc[mt][nt][0] * (1.0f - h0v * h0v),
                           acc[mt][nt][1] * (1.0f - h1v * h1v));
      unsigned p23 = pk2bf(acc[mt][nt][2] * (1.0f - h2v * h2v),
                           acc[mt][nt][3] * (1.0f - h3v * h3v));
      *(uint2*)(buf + (nt * 16 + ln) * AST + m0 + mt * 16 + q * 4) =
          make_uint2(p01, p23);
    }
  __syncthreads();

  // ================ GEMM5': gradH^T = W0 gz0^T ; symplectic float4 store ====
  // M=64 gradH-cols (4 tiles), N=64 samples: wave = m-tile (wave&3) x
  // 2 n-tiles ((wave>>2)*2 + {0,1}).
  {
    f32x4 acc5[2];
    acc5[0] = (f32x4){0.f, 0.f, 0.f, 0.f};
    acc5[1] = (f32x4){0.f, 0.f, 0.f, 0.f};
    const int mt5 = wave & 3;
    const int n0  = (wave >> 2) * 32;
    const u16* ap5 = p0b + (mt5 << 13) + lane * 8;   // (mt5*16+kc)*64*8
    #pragma unroll 2
    for (int kc = 0; kc < 16; ++kc) {
      s16x8 a = *(const s16x8*)(ap5 + (kc << 9));
      #pragma unroll
      for (int nt = 0; nt < 2; ++nt) {
        s16x8 b = *(const s16x8*)(buf + (n0 + nt * 16 + ln) * AST + kc * 32 + q * 8);
        acc5[nt] = MFMA_BF16(a, b, acc5[nt]);
      }
    }
    // C: row = gradH col g = mt5*16+q*4+r (quad never crosses 32), col = sample
    int g0 = mt5 * 16 + q * 4;
    int c0 = (g0 < 32) ? g0 + 32 : g0 - 32;   // out = [gradH_p, -gradH_q]
    float s = (g0 < 32) ? -1.0f : 1.0f;
    #pragma unroll
    for (int nt = 0; nt < 2; ++nt) {
      int smp = row0 + n0 + nt * 16 + ln;
      float4 v = make_float4(s * acc5[nt][0], s * acc5[nt][1],
                             s * acc5[nt][2], s * acc5[nt][3]);
      *(float4*)(out + (size_t)smp * 64 + c0) = v;
    }
  }
}

extern "C" void kernel_launch(void* const* d_in, const int* in_sizes, int n_in,
                              void* d_out, int out_size, void* d_ws, size_t ws_size,
                              hipStream_t stream) {
  // setup_inputs order: t, x, W0, b0, W1, b1, W2, b2, W3, b3
  const float* x  = (const float*)d_in[1];
  const float* W0 = (const float*)d_in[2];
  const float* b0 = (const float*)d_in[3];
  const float* W1 = (const float*)d_in[4];
  const float* b1 = (const float*)d_in[5];
  const float* W2 = (const float*)d_in[6];
  const float* b2 = (const float*)d_in[7];
  const float* W3 = (const float*)d_in[8];
  u16* ws = (u16*)d_ws;
  float* out = (float*)d_out;

  prep_weights<<<128, 256, 0, stream>>>(W0, W1, W2, W3, ws);
  hnn_fused<<<65536 / M_TILE, 512, 0, stream>>>(x, b0, b1, b2, ws, out);
}

// Round 14
// 244.569 us; speedup vs baseline: 1.0794x; 1.0794x over previous
//
#include <hip/hip_runtime.h>
#include <hip/hip_bf16.h>

typedef unsigned short u16;
typedef short s16x8 __attribute__((ext_vector_type(8)));
typedef float f32x4 __attribute__((ext_vector_type(4)));

#define MFMA_BF16(a, b, c) __builtin_amdgcn_mfma_f32_16x16x32_bf16((a), (b), (c), 0, 0, 0)

static constexpr int D_IN   = 64;
static constexpr int H_DIM  = 512;
static constexpr int M_TILE = 64;   // samples per block
static constexpr int AST    = 520;  // LDS row stride (bf16), rows = samples
static constexpr int XST    = 72;   // x-tile row stride

__device__ __forceinline__ u16 f2bf(float f) {
  unsigned u = __builtin_bit_cast(unsigned, f);
  u += 0x7fffu + ((u >> 16) & 1u);   // RNE
  return (u16)(u >> 16);
}
__device__ __forceinline__ float bfb2f(unsigned bits16) {
  return __builtin_bit_cast(float, bits16 << 16);
}
__device__ __forceinline__ float fast_tanh(float x) {
  float e = __expf(2.0f * x);
  return 1.0f - 2.0f * __builtin_amdgcn_rcpf(e + 1.0f);
}
// packed f32x2 -> bf16x2 (RNE). gfx950 has v_cvt_pk_bf16_f32; guarded fallback.
#if defined(__gfx950__) && __has_builtin(__builtin_amdgcn_cvt_pk_bf16_f32)
__device__ __forceinline__ unsigned pk2bf(float a, float b) {
  typedef __bf16 bf16x2_t __attribute__((ext_vector_type(2)));
  bf16x2_t v = __builtin_amdgcn_cvt_pk_bf16_f32(a, b);
  return __builtin_bit_cast(unsigned, v);
}
#else
__device__ __forceinline__ unsigned pk2bf(float a, float b) {
  return (unsigned)f2bf(a) | ((unsigned)f2bf(b) << 16);
}
#endif

// ---- prep: fp32 weights -> bf16, frag-packed (idx=lane&15, k=quad*8+j) ----
// Consumed as the A-operand of the TRANSPOSED GEMMs (h^T: M=feature, N=sample).
// W3 folded into p2b. ws layout: p0f[64x512] p0b[512x64] p1f p1b p2f p2b.
__global__ void prep_weights(const float* __restrict__ W0,
                             const float* __restrict__ W1,
                             const float* __restrict__ W2,
                             const float* __restrict__ W3,
                             u16* __restrict__ ws) {
  u16* p0f = ws;                       // fwd W0^T: M=512 feat, K=64
  u16* p0b = p0f + D_IN * H_DIM;       // GEMM5: M=64 gradH-col, K=512
  u16* p1f = p0b + D_IN * H_DIM;
  u16* p1b = p1f + H_DIM * H_DIM;
  u16* p2f = p1b + H_DIM * H_DIM;
  u16* p2b = p2f + H_DIM * H_DIM;

  int t = blockIdx.x * 256 + threadIdx.x;   // 32768 threads
  int lane = t & 63;
  int kc   = (t >> 6) & 15;
  int ntg  = t >> 10;                       // 0..31
  int ln = lane & 15, q = lane >> 4;
  int n = ntg * 16 + ln;                    // feature index (frag idx)
  int k = kc * 32 + q * 8;

  #pragma unroll
  for (int j = 0; j < 8; ++j) {
    p1f[t * 8 + j] = f2bf(W1[(k + j) * 512 + n]);             // A[m=n][k] = W1^T
    p2f[t * 8 + j] = f2bf(W2[(k + j) * 512 + n]);
    p1b[t * 8 + j] = f2bf(W1[n * 512 + (k + j)]);             // A[n][m] = W1
    p2b[t * 8 + j] = f2bf(W2[n * 512 + (k + j)] * W3[k + j]); // W3 folded
  }
  if (kc < 2) {  // W0^T fwd: K=64
    int t0 = (ntg * 2 + kc) * 64 + lane;
    #pragma unroll
    for (int j = 0; j < 8; ++j)
      p0f[t0 * 8 + j] = f2bf(W0[(k + j) * 512 + n]);
  }
  if (ntg < 4) { // GEMM5: A[d][m] = W0[d][m], d<64
    int t0 = (ntg * 16 + kc) * 64 + lane;
    #pragma unroll
    for (int j = 0; j < 8; ++j)
      p0b[t0 * 8 + j] = f2bf(W0[n * 512 + (k + j)]);
  }
}

// Wave's 4 A-tiles (weights) of k-chunk KC -> VGPRs, contiguous 1KB each.
#define LOAD_W4(BP, KC, WA)                                                     \
  {                                                                             \
    const u16* _sr = (BP) + ((size_t)wave << 15) + ((KC) << 9) + lane * 8;      \
    _Pragma("unroll")                                                           \
    for (int s = 0; s < 4; ++s)                                                 \
      (WA)[s] = *(const s16x8*)(_sr + (s << 13));                               \
  }
// 2-deep prologue (round-14 register diet: 3-deep spilled past the 128-arch
// split; depth 2 vs 3 measured neutral in rounds 10/12).
#define WA_PROLOGUE2(BP)                                                        \
  { LOAD_W4(BP, 0, wa0); LOAD_W4(BP, 1, wa1); }

// One K-step: B-frags (activations, 4 sample-tiles) from LDS, 16 MFMAs,
// refill WA with chunk KC+2.  D[feat][sample] = W-frag x h-frag.
#define STEP2(KC, WA, BP)                                                       \
  {                                                                             \
    s16x8 b[4];                                                                 \
    _Pragma("unroll")                                                           \
    for (int nt = 0; nt < 4; ++nt)                                              \
      b[nt] = *(const s16x8*)(buf + (nt * 16 + ln) * AST + (KC) * 32 + q * 8);  \
    _Pragma("unroll")                                                           \
    for (int nt = 0; nt < 4; ++nt)                                              \
      _Pragma("unroll")                                                         \
      for (int mt = 0; mt < 4; ++mt)                                            \
        acc[mt][nt] = MFMA_BF16((WA)[mt], b[nt], acc[mt][nt]);                  \
    if ((KC) + 2 < 16) LOAD_W4(BP, (KC) + 2, WA);                               \
  }

#define GEMM512_REG(BP)                                                         \
  {                                                                             \
    STEP2( 0, wa0, BP); STEP2( 1, wa1, BP);                                     \
    STEP2( 2, wa0, BP); STEP2( 3, wa1, BP);                                     \
    STEP2( 4, wa0, BP); STEP2( 5, wa1, BP);                                     \
    STEP2( 6, wa0, BP); STEP2( 7, wa1, BP);                                     \
    STEP2( 8, wa0, BP); STEP2( 9, wa1, BP);                                     \
    STEP2(10, wa0, BP); STEP2(11, wa1, BP);                                     \
    STEP2(12, wa0, BP); STEP2(13, wa1, BP);                                     \
    STEP2(14, wa0, BP); STEP2(15, wa1, BP);                                     \
  }

// acc init = bias broadcast (C-rows are features -> bias varies with q*4+r).
#define ACC_INIT_BIAS(BIAS)                                                     \
  {                                                                             \
    _Pragma("unroll")                                                           \
    for (int mt = 0; mt < 4; ++mt) {                                            \
      float4 bv = *(const float4*)((BIAS) + wave * 64 + mt * 16 + q * 4);       \
      _Pragma("unroll")                                                         \
      for (int nt = 0; nt < 4; ++nt)                                            \
        acc[mt][nt] = (f32x4){bv.x, bv.y, bv.z, bv.w};                          \
    }                                                                           \
  }
#define ACC_INIT_ZERO()                                                         \
  {                                                                             \
    _Pragma("unroll") for (int mt = 0; mt < 4; ++mt)                            \
      _Pragma("unroll") for (int nt = 0; nt < 4; ++nt)                          \
        acc[mt][nt] = (f32x4){0.f, 0.f, 0.f, 0.f};                              \
  }

// block=512 (8 waves); wave = 64 features x 64 samples (4 m x 4 n tiles).
// Transposed orientation: lane's 4 C-values = 4 consecutive FEATURES ->
// epilogue LDS writes are b64 (16/epilogue vs 64 scalar b16).
// Register rule learned rounds 5/11/13: with AGPRs in use the unified file
// splits 128 arch / 128 AGPR at 2 waves/SIMD — keep arch <= ~124.
__global__ __launch_bounds__(512, 2) void hnn_fused(
    const float* __restrict__ x,
    const float* __restrict__ bias0,
    const float* __restrict__ bias1,
    const float* __restrict__ bias2,
    const u16* __restrict__ ws,
    float* __restrict__ out)
{
  const u16* p0f = ws;
  const u16* p0b = p0f + D_IN * H_DIM;
  const u16* p1f = p0b + D_IN * H_DIM;
  const u16* p1b = p1f + H_DIM * H_DIM;
  const u16* p2f = p1b + H_DIM * H_DIM;
  const u16* p2b = p2f + H_DIM * H_DIM;

  __shared__ __align__(16) u16 xs[M_TILE * XST];    // 9 KB  [sample][in-feat]
  __shared__ __align__(16) u16 buf[M_TILE * AST];   // 65 KB [sample][feat]

  const int tid  = threadIdx.x;
  const int wave = tid >> 6;      // 0..7 -> owns features wave*64..+63
  const int lane = tid & 63;
  const int ln   = lane & 15;
  const int q    = lane >> 4;
  const int m0   = wave * 64;     // wave's feature base
  const int row0 = blockIdx.x * M_TILE;

  // ---- stage x tile: 64x64 fp32 -> bf16 LDS [sample][feat] ----
  {
    int r = tid >> 3, c = (tid & 7) * 8;
    const float4* src = (const float4*)(x + (size_t)(row0 + r) * D_IN + c);
    float4 f0 = src[0];
    float4 f1 = src[1];
    u16* dst = xs + r * XST + c;
    dst[0] = f2bf(f0.x); dst[1] = f2bf(f0.y); dst[2] = f2bf(f0.z); dst[3] = f2bf(f0.w);
    dst[4] = f2bf(f1.x); dst[5] = f2bf(f1.y); dst[6] = f2bf(f1.z); dst[7] = f2bf(f1.w);
  }
  __syncthreads();

  f32x4 acc[4][4];
  s16x8 wa0[4], wa1[4];           // 2-deep weight (A-operand) rotation
  unsigned h0p[4][4][2];          // h packed bf16x2, C-layout (tanh' in bwd)
  unsigned h1p[4][4][2];

  // ================ GEMM0': z0^T = W0^T x^T + b0 (K=64) ================
  ACC_INIT_BIAS(bias0);
  {
    const u16* ap0 = p0f + (wave << 12) + lane * 8;
    #pragma unroll
    for (int kc = 0; kc < 2; ++kc) {
      s16x8 b[4];
      #pragma unroll
      for (int nt = 0; nt < 4; ++nt)
        b[nt] = *(const s16x8*)(xs + (nt * 16 + ln) * XST + kc * 32 + q * 8);
      #pragma unroll
      for (int mt = 0; mt < 4; ++mt) {
        s16x8 a = *(const s16x8*)(ap0 + (mt << 10) + (kc << 9));
        #pragma unroll
        for (int nt = 0; nt < 4; ++nt)
          acc[mt][nt] = MFMA_BF16(a, b[nt], acc[mt][nt]);
      }
    }
  }
  WA_PROLOGUE2(p1f);   // prefetch GEMM1 weights; overlaps epilogue VALU
  // epilogue: h0 = tanh(z0) -> pack regs + one b64 LDS write per tile
  #pragma unroll
  for (int mt = 0; mt < 4; ++mt)
    #pragma unroll
    for (int nt = 0; nt < 4; ++nt) {
      unsigned p01 = pk2bf(fast_tanh(acc[mt][nt][0]), fast_tanh(acc[mt][nt][1]));
      unsigned p23 = pk2bf(fast_tanh(acc[mt][nt][2]), fast_tanh(acc[mt][nt][3]));
      h0p[mt][nt][0] = p01; h0p[mt][nt][1] = p23;
      *(uint2*)(buf + (nt * 16 + ln) * AST + m0 + mt * 16 + q * 4) =
          make_uint2(p01, p23);
    }
  __syncthreads();

  // ================ GEMM1': z1^T = W1^T h0^T + b1 ================
  ACC_INIT_BIAS(bias1);
  GEMM512_REG(p1f);
  __syncthreads();       // all waves done reading h0 (buf)
  WA_PROLOGUE2(p2f);
  #pragma unroll
  for (int mt = 0; mt < 4; ++mt)
    #pragma unroll
    for (int nt = 0; nt < 4; ++nt) {
      unsigned p01 = pk2bf(fast_tanh(acc[mt][nt][0]), fast_tanh(acc[mt][nt][1]));
      unsigned p23 = pk2bf(fast_tanh(acc[mt][nt][2]), fast_tanh(acc[mt][nt][3]));
      h1p[mt][nt][0] = p01; h1p[mt][nt][1] = p23;
      *(uint2*)(buf + (nt * 16 + ln) * AST + m0 + mt * 16 + q * 4) =
          make_uint2(p01, p23);
    }
  __syncthreads();

  // ================ GEMM2': z2^T ; gz2° = (1-h2^2)  (W3 folded in p2b) ======
  ACC_INIT_BIAS(bias2);
  GEMM512_REG(p2f);
  __syncthreads();
  WA_PROLOGUE2(p2b);
  #pragma unroll
  for (int mt = 0; mt < 4; ++mt)
    #pragma unroll
    for (int nt = 0; nt < 4; ++nt) {
      float t0 = fast_tanh(acc[mt][nt][0]), t1 = fast_tanh(acc[mt][nt][1]);
      float t2 = fast_tanh(acc[mt][nt][2]), t3 = fast_tanh(acc[mt][nt][3]);
      unsigned p01 = pk2bf(1.0f - t0 * t0, 1.0f - t1 * t1);
      unsigned p23 = pk2bf(1.0f - t2 * t2, 1.0f - t3 * t3);
      *(uint2*)(buf + (nt * 16 + ln) * AST + m0 + mt * 16 + q * 4) =
          make_uint2(p01, p23);
    }
  __syncthreads();

  // ================ GEMM3': g1^T = (W2*W3) gz2°^T ; gz1 = g1*(1-h1^2) =======
  ACC_INIT_ZERO();
  GEMM512_REG(p2b);
  __syncthreads();
  WA_PROLOGUE2(p1b);
  #pragma unroll
  for (int mt = 0; mt < 4; ++mt)
    #pragma unroll
    for (int nt = 0; nt < 4; ++nt) {
      unsigned pa = h1p[mt][nt][0], pb = h1p[mt][nt][1];
      float h0v = bfb2f(pa & 0xffffu), h1v = bfb2f(pa >> 16);
      float h2v = bfb2f(pb & 0xffffu), h3v = bfb2f(pb >> 16);
      unsigned p01 = pk2bf(acc[mt][nt][0] * (1.0f - h0v * h0v),
                           acc[mt][nt][1] * (1.0f - h1v * h1v));
      unsigned p23 = pk2bf(acc[mt][nt][2] * (1.0f - h2v * h2v),
                           acc[mt][nt][3] * (1.0f - h3v * h3v));
      *(uint2*)(buf + (nt * 16 + ln) * AST + m0 + mt * 16 + q * 4) =
          make_uint2(p01, p23);
    }
  __syncthreads();

  // ================ GEMM4': g0^T = W1 gz1^T ; gz0 = g0*(1-h0^2) =============
  ACC_INIT_ZERO();
  GEMM512_REG(p1b);
  __syncthreads();
  #pragma unroll
  for (int mt = 0; mt < 4; ++mt)
    #pragma unroll
    for (int nt = 0; nt < 4; ++nt) {
      unsigned pa = h0p[mt][nt][0], pb = h0p[mt][nt][1];
      float h0v = bfb2f(pa & 0xffffu), h1v = bfb2f(pa >> 16);
      float h2v = bfb2f(pb & 0xffffu), h3v = bfb2f(pb >> 16);
      unsigned p01 = pk2bf(acc[mt][nt][0] * (1.0f - h0v * h0v),
                           acc[mt][nt][1] * (1.0f - h1v * h1v));
      unsigned p23 = pk2bf(acc[mt][nt][2] * (1.0f - h2v * h2v),
                           acc[mt][nt][3] * (1.0f - h3v * h3v));
      *(uint2*)(buf + (nt * 16 + ln) * AST + m0 + mt * 16 + q * 4) =
          make_uint2(p01, p23);
    }
  __syncthreads();

  // ================ GEMM5': gradH^T = W0 gz0^T ; symplectic float4 store ====
  {
    f32x4 acc5[2];
    acc5[0] = (f32x4){0.f, 0.f, 0.f, 0.f};
    acc5[1] = (f32x4){0.f, 0.f, 0.f, 0.f};
    const int mt5 = wave & 3;
    const int n0  = (wave >> 2) * 32;
    const u16* ap5 = p0b + (mt5 << 13) + lane * 8;   // (mt5*16+kc)*64*8
    #pragma unroll 2
    for (int kc = 0; kc < 16; ++kc) {
      s16x8 a = *(const s16x8*)(ap5 + (kc << 9));
      #pragma unroll
      for (int nt = 0; nt < 2; ++nt) {
        s16x8 b = *(const s16x8*)(buf + (n0 + nt * 16 + ln) * AST + kc * 32 + q * 8);
        acc5[nt] = MFMA_BF16(a, b, acc5[nt]);
      }
    }
    // C: row = gradH col g = mt5*16+q*4+r (quad never crosses 32), col = sample
    int g0 = mt5 * 16 + q * 4;
    int c0 = (g0 < 32) ? g0 + 32 : g0 - 32;   // out = [gradH_p, -gradH_q]
    float s = (g0 < 32) ? -1.0f : 1.0f;
    #pragma unroll
    for (int nt = 0; nt < 2; ++nt) {
      int smp = row0 + n0 + nt * 16 + ln;
      float4 v = make_float4(s * acc5[nt][0], s * acc5[nt][1],
                             s * acc5[nt][2], s * acc5[nt][3]);
      *(float4*)(out + (size_t)smp * 64 + c0) = v;
    }
  }
}

extern "C" void kernel_launch(void* const* d_in, const int* in_sizes, int n_in,
                              void* d_out, int out_size, void* d_ws, size_t ws_size,
                              hipStream_t stream) {
  // setup_inputs order: t, x, W0, b0, W1, b1, W2, b2, W3, b3
  const float* x  = (const float*)d_in[1];
  const float* W0 = (const float*)d_in[2];
  const float* b0 = (const float*)d_in[3];
  const float* W1 = (const float*)d_in[4];
  const float* b1 = (const float*)d_in[5];
  const float* W2 = (const float*)d_in[6];
  const float* b2 = (const float*)d_in[7];
  const float* W3 = (const float*)d_in[8];
  u16* ws = (u16*)d_ws;
  float* out = (float*)d_out;

  prep_weights<<<128, 256, 0, stream>>>(W0, W1, W2, W3, ws);
  hnn_fused<<<65536 / M_TILE, 512, 0, stream>>>(x, b0, b1, b2, ws, out);
}

// Round 15
// 229.224 us; speedup vs baseline: 1.1517x; 1.0669x over previous
//
#include <hip/hip_runtime.h>
#include <hip/hip_bf16.h>

typedef unsigned short u16;
typedef short s16x8 __attribute__((ext_vector_type(8)));
typedef float f32x4 __attribute__((ext_vector_type(4)));

#define MFMA_BF16(a, b, c) __builtin_amdgcn_mfma_f32_16x16x32_bf16((a), (b), (c), 0, 0, 0)

static constexpr int D_IN   = 64;
static constexpr int H_DIM  = 512;
static constexpr int M_TILE = 64;   // samples per block
static constexpr int AST    = 520;  // LDS row stride (bf16), rows = samples
static constexpr int XST    = 72;   // x-tile row stride

__device__ __forceinline__ u16 f2bf(float f) {
  unsigned u = __builtin_bit_cast(unsigned, f);
  u += 0x7fffu + ((u >> 16) & 1u);   // RNE
  return (u16)(u >> 16);
}
__device__ __forceinline__ float bfb2f(unsigned bits16) {
  return __builtin_bit_cast(float, bits16 << 16);
}
__device__ __forceinline__ float fast_tanh(float x) {
  float e = __expf(2.0f * x);
  return 1.0f - 2.0f * __builtin_amdgcn_rcpf(e + 1.0f);
}
// packed f32x2 -> bf16x2 (RNE). gfx950 has v_cvt_pk_bf16_f32; guarded fallback.
#if defined(__gfx950__) && __has_builtin(__builtin_amdgcn_cvt_pk_bf16_f32)
__device__ __forceinline__ unsigned pk2bf(float a, float b) {
  typedef __bf16 bf16x2_t __attribute__((ext_vector_type(2)));
  bf16x2_t v = __builtin_amdgcn_cvt_pk_bf16_f32(a, b);
  return __builtin_bit_cast(unsigned, v);
}
#else
__device__ __forceinline__ unsigned pk2bf(float a, float b) {
  return (unsigned)f2bf(a) | ((unsigned)f2bf(b) << 16);
}
#endif

// ---- prep: fp32 weights -> bf16, frag-packed (idx=lane&15, k=quad*8+j) ----
// Consumed as the A-operand of the TRANSPOSED GEMMs (h^T: M=feature, N=sample).
// W3 folded into p2b. ws layout: p0f[64x512] p0b[512x64] p1f p1b p2f p2b.
__global__ void prep_weights(const float* __restrict__ W0,
                             const float* __restrict__ W1,
                             const float* __restrict__ W2,
                             const float* __restrict__ W3,
                             u16* __restrict__ ws) {
  u16* p0f = ws;                       // fwd W0^T: M=512 feat, K=64
  u16* p0b = p0f + D_IN * H_DIM;       // GEMM5: M=64 gradH-col, K=512
  u16* p1f = p0b + D_IN * H_DIM;
  u16* p1b = p1f + H_DIM * H_DIM;
  u16* p2f = p1b + H_DIM * H_DIM;
  u16* p2b = p2f + H_DIM * H_DIM;

  int t = blockIdx.x * 256 + threadIdx.x;   // 32768 threads
  int lane = t & 63;
  int kc   = (t >> 6) & 15;
  int ntg  = t >> 10;                       // 0..31
  int ln = lane & 15, q = lane >> 4;
  int n = ntg * 16 + ln;                    // feature index (frag idx)
  int k = kc * 32 + q * 8;

  #pragma unroll
  for (int j = 0; j < 8; ++j) {
    p1f[t * 8 + j] = f2bf(W1[(k + j) * 512 + n]);             // A[m=n][k] = W1^T
    p2f[t * 8 + j] = f2bf(W2[(k + j) * 512 + n]);
    p1b[t * 8 + j] = f2bf(W1[n * 512 + (k + j)]);             // A[n][m] = W1
    p2b[t * 8 + j] = f2bf(W2[n * 512 + (k + j)] * W3[k + j]); // W3 folded
  }
  if (kc < 2) {  // W0^T fwd: K=64
    int t0 = (ntg * 2 + kc) * 64 + lane;
    #pragma unroll
    for (int j = 0; j < 8; ++j)
      p0f[t0 * 8 + j] = f2bf(W0[(k + j) * 512 + n]);
  }
  if (ntg < 4) { // GEMM5: A[d][m] = W0[d][m], d<64
    int t0 = (ntg * 16 + kc) * 64 + lane;
    #pragma unroll
    for (int j = 0; j < 8; ++j)
      p0b[t0 * 8 + j] = f2bf(W0[n * 512 + (k + j)]);
  }
}

// Wave's 4 A-tiles (weights) of k-chunk KC -> VGPRs, contiguous 1KB each.
#define LOAD_W4(BP, KC, WA)                                                     \
  {                                                                             \
    const u16* _sr = (BP) + ((size_t)wave << 15) + ((KC) << 9) + lane * 8;      \
    _Pragma("unroll")                                                           \
    for (int s = 0; s < 4; ++s)                                                 \
      (WA)[s] = *(const s16x8*)(_sr + (s << 13));                               \
  }
#define WA_PROLOGUE2(BP)                                                        \
  { LOAD_W4(BP, 0, wa0); LOAD_W4(BP, 1, wa1); }

// One K-step: B-frags (activations, 4 sample-tiles) from LDS buffer BUF,
// 16 MFMAs, refill WA with chunk KC+2.
#define STEP2(KC, WA, BP, BUF)                                                  \
  {                                                                             \
    s16x8 b[4];                                                                 \
    _Pragma("unroll")                                                           \
    for (int nt = 0; nt < 4; ++nt)                                              \
      b[nt] = *(const s16x8*)((BUF) + (nt * 16 + ln) * AST + (KC) * 32 + q * 8);\
    _Pragma("unroll")                                                           \
    for (int nt = 0; nt < 4; ++nt)                                              \
      _Pragma("unroll")                                                         \
      for (int mt = 0; mt < 4; ++mt)                                            \
        acc[mt][nt] = MFMA_BF16((WA)[mt], b[nt], acc[mt][nt]);                  \
    if ((KC) + 2 < 16) LOAD_W4(BP, (KC) + 2, WA);                               \
  }

#define GEMM512_REG(BP, BUF)                                                    \
  {                                                                             \
    STEP2( 0, wa0, BP, BUF); STEP2( 1, wa1, BP, BUF);                           \
    STEP2( 2, wa0, BP, BUF); STEP2( 3, wa1, BP, BUF);                           \
    STEP2( 4, wa0, BP, BUF); STEP2( 5, wa1, BP, BUF);                           \
    STEP2( 6, wa0, BP, BUF); STEP2( 7, wa1, BP, BUF);                           \
    STEP2( 8, wa0, BP, BUF); STEP2( 9, wa1, BP, BUF);                           \
    STEP2(10, wa0, BP, BUF); STEP2(11, wa1, BP, BUF);                           \
    STEP2(12, wa0, BP, BUF); STEP2(13, wa1, BP, BUF);                           \
    STEP2(14, wa0, BP, BUF); STEP2(15, wa1, BP, BUF);                           \
  }

// acc init = bias broadcast (C-rows are features -> bias varies with q*4+r).
#define ACC_INIT_BIAS(BIAS)                                                     \
  {                                                                             \
    _Pragma("unroll")                                                           \
    for (int mt = 0; mt < 4; ++mt) {                                            \
      float4 bv = *(const float4*)((BIAS) + wave * 64 + mt * 16 + q * 4);       \
      _Pragma("unroll")                                                         \
      for (int nt = 0; nt < 4; ++nt)                                            \
        acc[mt][nt] = (f32x4){bv.x, bv.y, bv.z, bv.w};                          \
    }                                                                           \
  }
#define ACC_INIT_ZERO()                                                         \
  {                                                                             \
    _Pragma("unroll") for (int mt = 0; mt < 4; ++mt)                            \
      _Pragma("unroll") for (int nt = 0; nt < 4; ++nt)                          \
        acc[mt][nt] = (f32x4){0.f, 0.f, 0.f, 0.f};                              \
  }

// block=512 (8 waves); wave = 64 features x 64 samples. TRANSPOSED epilogues
// (b64 LDS writes). Register rule (rounds 5/11/13/14): with AGPRs in use the
// unified file splits 128 arch / 128 AGPR — arch must stay <= ~124.
// This round: occupancy is reg-capped at 1 block/CU anyway, so spend the idle
// LDS: TWO activation buffers (139KB total). h1 lives in bufB (no h1p regs,
// -32 arch), gz1 overwrites it in-place (lane-private addresses between
// barriers). Reader-buf != writer-buf everywhere -> ONE barrier per GEMM.
__global__ __launch_bounds__(512, 2) void hnn_fused(
    const float* __restrict__ x,
    const float* __restrict__ bias0,
    const float* __restrict__ bias1,
    const float* __restrict__ bias2,
    const u16* __restrict__ ws,
    float* __restrict__ out)
{
  const u16* p0f = ws;
  const u16* p0b = p0f + D_IN * H_DIM;
  const u16* p1f = p0b + D_IN * H_DIM;
  const u16* p1b = p1f + H_DIM * H_DIM;
  const u16* p2f = p1b + H_DIM * H_DIM;
  const u16* p2b = p2f + H_DIM * H_DIM;

  __shared__ __align__(16) u16 xs[M_TILE * XST];     // 9 KB  [sample][in-feat]
  __shared__ __align__(16) u16 bufA[M_TILE * AST];   // 65 KB h0 / gz2° / gz0
  __shared__ __align__(16) u16 bufB[M_TILE * AST];   // 65 KB h1 -> gz1 (in-place)

  const int tid  = threadIdx.x;
  const int wave = tid >> 6;      // 0..7 -> owns features wave*64..+63
  const int lane = tid & 63;
  const int ln   = lane & 15;
  const int q    = lane >> 4;
  const int m0   = wave * 64;     // wave's feature base
  const int row0 = blockIdx.x * M_TILE;

  // ---- stage x tile: 64x64 fp32 -> bf16 LDS [sample][feat] ----
  {
    int r = tid >> 3, c = (tid & 7) * 8;
    const float4* src = (const float4*)(x + (size_t)(row0 + r) * D_IN + c);
    float4 f0 = src[0];
    float4 f1 = src[1];
    u16* dst = xs + r * XST + c;
    dst[0] = f2bf(f0.x); dst[1] = f2bf(f0.y); dst[2] = f2bf(f0.z); dst[3] = f2bf(f0.w);
    dst[4] = f2bf(f1.x); dst[5] = f2bf(f1.y); dst[6] = f2bf(f1.z); dst[7] = f2bf(f1.w);
  }
  __syncthreads();

  f32x4 acc[4][4];
  s16x8 wa0[4], wa1[4];           // 2-deep weight (A-operand) rotation
  unsigned h0p[4][4][2];          // h0 packed bf16x2 (h1 lives in bufB)

  // ================ GEMM0': z0^T = W0^T x^T + b0 (K=64, reads xs) ===========
  ACC_INIT_BIAS(bias0);
  {
    const u16* ap0 = p0f + (wave << 12) + lane * 8;
    #pragma unroll
    for (int kc = 0; kc < 2; ++kc) {
      s16x8 b[4];
      #pragma unroll
      for (int nt = 0; nt < 4; ++nt)
        b[nt] = *(const s16x8*)(xs + (nt * 16 + ln) * XST + kc * 32 + q * 8);
      #pragma unroll
      for (int mt = 0; mt < 4; ++mt) {
        s16x8 a = *(const s16x8*)(ap0 + (mt << 10) + (kc << 9));
        #pragma unroll
        for (int nt = 0; nt < 4; ++nt)
          acc[mt][nt] = MFMA_BF16(a, b[nt], acc[mt][nt]);
      }
    }
  }
  WA_PROLOGUE2(p1f);   // prefetch GEMM1 weights; overlaps epilogue VALU
  // epilogue: h0 = tanh(z0) -> h0p regs + bufA (xs != bufA: no pre-barrier)
  #pragma unroll
  for (int mt = 0; mt < 4; ++mt)
    #pragma unroll
    for (int nt = 0; nt < 4; ++nt) {
      unsigned p01 = pk2bf(fast_tanh(acc[mt][nt][0]), fast_tanh(acc[mt][nt][1]));
      unsigned p23 = pk2bf(fast_tanh(acc[mt][nt][2]), fast_tanh(acc[mt][nt][3]));
      h0p[mt][nt][0] = p01; h0p[mt][nt][1] = p23;
      *(uint2*)(bufA + (nt * 16 + ln) * AST + m0 + mt * 16 + q * 4) =
          make_uint2(p01, p23);
    }
  __syncthreads();   // bufA = h0 ready

  // ================ GEMM1': z1^T = W1^T h0^T + b1 (reads bufA -> bufB) ======
  ACC_INIT_BIAS(bias1);
  GEMM512_REG(p1f, bufA);
  WA_PROLOGUE2(p2f);
  #pragma unroll
  for (int mt = 0; mt < 4; ++mt)
    #pragma unroll
    for (int nt = 0; nt < 4; ++nt) {
      unsigned p01 = pk2bf(fast_tanh(acc[mt][nt][0]), fast_tanh(acc[mt][nt][1]));
      unsigned p23 = pk2bf(fast_tanh(acc[mt][nt][2]), fast_tanh(acc[mt][nt][3]));
      *(uint2*)(bufB + (nt * 16 + ln) * AST + m0 + mt * 16 + q * 4) =
          make_uint2(p01, p23);
    }
  __syncthreads();   // bufB = h1 ready

  // ================ GEMM2': z2^T ; gz2° = (1-h2^2)  (reads bufB -> bufA) ====
  ACC_INIT_BIAS(bias2);
  GEMM512_REG(p2f, bufB);
  WA_PROLOGUE2(p2b);
  #pragma unroll
  for (int mt = 0; mt < 4; ++mt)
    #pragma unroll
    for (int nt = 0; nt < 4; ++nt) {
      float t0 = fast_tanh(acc[mt][nt][0]), t1 = fast_tanh(acc[mt][nt][1]);
      float t2 = fast_tanh(acc[mt][nt][2]), t3 = fast_tanh(acc[mt][nt][3]);
      unsigned p01 = pk2bf(1.0f - t0 * t0, 1.0f - t1 * t1);
      unsigned p23 = pk2bf(1.0f - t2 * t2, 1.0f - t3 * t3);
      *(uint2*)(bufA + (nt * 16 + ln) * AST + m0 + mt * 16 + q * 4) =
          make_uint2(p01, p23);
    }
  __syncthreads();   // bufA = gz2° ready

  // ===== GEMM3': g1^T = (W2*W3) gz2°^T ; gz1 = g1*(1-h1^2) (bufA -> bufB) ===
  // h1 re-read from bufB (the registers we no longer spend); gz1 overwrites
  // the same lane-private address.
  ACC_INIT_ZERO();
  GEMM512_REG(p2b, bufA);
  WA_PROLOGUE2(p1b);
  #pragma unroll
  for (int mt = 0; mt < 4; ++mt)
    #pragma unroll
    for (int nt = 0; nt < 4; ++nt) {
      uint2* hp = (uint2*)(bufB + (nt * 16 + ln) * AST + m0 + mt * 16 + q * 4);
      uint2 hv = *hp;
      float h0v = bfb2f(hv.x & 0xffffu), h1v = bfb2f(hv.x >> 16);
      float h2v = bfb2f(hv.y & 0xffffu), h3v = bfb2f(hv.y >> 16);
      unsigned p01 = pk2bf(acc[mt][nt][0] * (1.0f - h0v * h0v),
                           acc[mt][nt][1] * (1.0f - h1v * h1v));
      unsigned p23 = pk2bf(acc[mt][nt][2] * (1.0f - h2v * h2v),
                           acc[mt][nt][3] * (1.0f - h3v * h3v));
      *hp = make_uint2(p01, p23);
    }
  __syncthreads();   // bufB = gz1 ready

  // ================ GEMM4': g0^T = W1 gz1^T ; gz0 = g0*(1-h0^2) (bufB->bufA) =
  ACC_INIT_ZERO();
  GEMM512_REG(p1b, bufB);
  #pragma unroll
  for (int mt = 0; mt < 4; ++mt)
    #pragma unroll
    for (int nt = 0; nt < 4; ++nt) {
      unsigned pa = h0p[mt][nt][0], pb = h0p[mt][nt][1];
      float h0v = bfb2f(pa & 0xffffu), h1v = bfb2f(pa >> 16);
      float h2v = bfb2f(pb & 0xffffu), h3v = bfb2f(pb >> 16);
      unsigned p01 = pk2bf(acc[mt][nt][0] * (1.0f - h0v * h0v),
                           acc[mt][nt][1] * (1.0f - h1v * h1v));
      unsigned p23 = pk2bf(acc[mt][nt][2] * (1.0f - h2v * h2v),
                           acc[mt][nt][3] * (1.0f - h3v * h3v));
      *(uint2*)(bufA + (nt * 16 + ln) * AST + m0 + mt * 16 + q * 4) =
          make_uint2(p01, p23);
    }
  __syncthreads();   // bufA = gz0 ready

  // ================ GEMM5': gradH^T = W0 gz0^T ; symplectic float4 store ====
  {
    f32x4 acc5[2];
    acc5[0] = (f32x4){0.f, 0.f, 0.f, 0.f};
    acc5[1] = (f32x4){0.f, 0.f, 0.f, 0.f};
    const int mt5 = wave & 3;
    const int n0  = (wave >> 2) * 32;
    const u16* ap5 = p0b + (mt5 << 13) + lane * 8;   // (mt5*16+kc)*64*8
    #pragma unroll 2
    for (int kc = 0; kc < 16; ++kc) {
      s16x8 a = *(const s16x8*)(ap5 + (kc << 9));
      #pragma unroll
      for (int nt = 0; nt < 2; ++nt) {
        s16x8 b = *(const s16x8*)(bufA + (n0 + nt * 16 + ln) * AST + kc * 32 + q * 8);
        acc5[nt] = MFMA_BF16(a, b, acc5[nt]);
      }
    }
    // C: row = gradH col g = mt5*16+q*4+r (quad never crosses 32), col = sample
    int g0 = mt5 * 16 + q * 4;
    int c0 = (g0 < 32) ? g0 + 32 : g0 - 32;   // out = [gradH_p, -gradH_q]
    float s = (g0 < 32) ? -1.0f : 1.0f;
    #pragma unroll
    for (int nt = 0; nt < 2; ++nt) {
      int smp = row0 + n0 + nt * 16 + ln;
      float4 v = make_float4(s * acc5[nt][0], s * acc5[nt][1],
                             s * acc5[nt][2], s * acc5[nt][3]);
      *(float4*)(out + (size_t)smp * 64 + c0) = v;
    }
  }
}

extern "C" void kernel_launch(void* const* d_in, const int* in_sizes, int n_in,
                              void* d_out, int out_size, void* d_ws, size_t ws_size,
                              hipStream_t stream) {
  // setup_inputs order: t, x, W0, b0, W1, b1, W2, b2, W3, b3
  const float* x  = (const float*)d_in[1];
  const float* W0 = (const float*)d_in[2];
  const float* b0 = (const float*)d_in[3];
  const float* W1 = (const float*)d_in[4];
  const float* b1 = (const float*)d_in[5];
  const float* W2 = (const float*)d_in[6];
  const float* b2 = (const float*)d_in[7];
  const float* W3 = (const float*)d_in[8];
  u16* ws = (u16*)d_ws;
  float* out = (float*)d_out;

  prep_weights<<<128, 256, 0, stream>>>(W0, W1, W2, W3, ws);
  hnn_fused<<<65536 / M_TILE, 512, 0, stream>>>(x, b0, b1, b2, ws, out);
}